// Round 3
// baseline (389.166 us; speedup 1.0000x reference)
//
#include <hip/hip_runtime.h>

// TreeAttentionV2: B=8, T=1024, C=1024 (L=4,R=256), H=16, hd=64.
// Pipeline (all fp16 MFMA, fp32 accumulate):
//   1. conv_x:      x fp32 (8192x1024) -> xh fp16
//   2. tconv:       w_attn fp32 (1024x3072) -> waT fp16 (3072x1024)   [B^T for GEMM]
//   3. tconv:       w_proj fp32 (1024x1024) -> wpT fp16 (1024x1024)
//   4. gemm<f16>:   qkv = xh @ waT^T + b_attn  -> fp16 (8192x3072)
//   5. vtrans:      v section -> vT (128 heads)(64 x 1024)            [V^T for PV MFMA]
//   6. attn v3:     512 thr / 8 waves. Phase1: S^T=K.Q^T, exp->E(LDS, swizzled),
//                   rowsum in regs -> lsum. Phase2: packed-fp16 RMW p=relu(e*inv-t).
//                   Phase3: per-wave 16x16 output tile over full k (no reduce).
//   7. gemm<f32>:   out = y @ wpT^T + b_proj -> fp32 d_out
//
// Workspace layout (needs >= 92,274,688 B):
//   [0, 48M)   qkv fp16
//   [48M,64M)  vT  fp16
//   [64M,80M)  xh fp16 (reused as y after gemm1 consumes it)
//   [80M,86M)  waT fp16
//   [86M,88M)  wpT fp16

typedef _Float16 half8 __attribute__((ext_vector_type(8)));
typedef _Float16 half4_t __attribute__((ext_vector_type(4)));
typedef float floatx4 __attribute__((ext_vector_type(4)));

__device__ __forceinline__ void gl2lds16(const void* gsrc, void* lds) {
    __builtin_amdgcn_global_load_lds(
        (const __attribute__((address_space(1))) unsigned int*)gsrc,
        (__attribute__((address_space(3))) unsigned int*)lds,
        16, 0, 0);
}

// ---------------- elementwise convert fp32 -> fp16 ----------------
__global__ __launch_bounds__(256) void conv_x(const float4* __restrict__ in,
                                              _Float16* __restrict__ out, int n4) {
    int idx = blockIdx.x * blockDim.x + threadIdx.x;
    int stride = gridDim.x * blockDim.x;
    for (int i = idx; i < n4; i += stride) {
        float4 v = in[i];
        half4_t h = { (_Float16)v.x, (_Float16)v.y, (_Float16)v.z, (_Float16)v.w };
        *(half4_t*)(out + (size_t)i * 4) = h;
    }
}

// ------------- transpose + convert: out[n][k] = in[k][n] ----------
__global__ __launch_bounds__(256) void tconv(const float* __restrict__ in,
                                             _Float16* __restrict__ out, int R, int C) {
    __shared__ _Float16 t[64 * 65];
    int bx = blockIdx.x, by = blockIdx.y;
#pragma unroll
    for (int it = 0; it < 16; ++it) {
        int idx = it * 256 + threadIdx.x;
        int r = idx >> 6, c = idx & 63;
        t[c * 65 + r] = (_Float16)in[(size_t)(by * 64 + r) * C + bx * 64 + c];
    }
    __syncthreads();
#pragma unroll
    for (int it = 0; it < 16; ++it) {
        int idx = it * 256 + threadIdx.x;
        int rn = idx >> 6, ck = idx & 63;
        out[(size_t)(bx * 64 + rn) * R + by * 64 + ck] = t[rn * 65 + ck];
    }
}

// ------------- V transpose: vT[bh*64+d][t] = qkv[b,t, 2048+h*64+d] -------------
__global__ __launch_bounds__(256) void vtrans(const _Float16* __restrict__ qkv,
                                              _Float16* __restrict__ vT) {
    __shared__ _Float16 t[64 * 65];
    int t0 = blockIdx.x * 64;
    int bh = blockIdx.y;
    int b = bh >> 4, h = bh & 15;
#pragma unroll
    for (int it = 0; it < 16; ++it) {
        int idx = it * 256 + threadIdx.x;
        int tt = idx >> 6, d = idx & 63;
        t[d * 65 + tt] = qkv[(size_t)(b * 1024 + t0 + tt) * 3072 + 2048 + h * 64 + d];
    }
    __syncthreads();
#pragma unroll
    for (int it = 0; it < 16; ++it) {
        int idx = it * 256 + threadIdx.x;
        int dd = idx >> 6, tt = idx & 63;
        vT[(size_t)(bh * 64 + dd) * 1024 + t0 + tt] = t[dd * 65 + tt];
    }
}

// ------------- m97-style GEMM: C(MxN) = A(MxK) * BT(NxK)^T + bias -------------
template <bool F16OUT>
__global__ __launch_bounds__(256) void gemm_tn(const _Float16* __restrict__ A,
                                               const _Float16* __restrict__ BT,
                                               const float* __restrict__ bias,
                                               void* __restrict__ Cout, int N) {
    constexpr int K = 1024;
    __shared__ __attribute__((aligned(16))) _Float16 sA[128 * 32];
    __shared__ __attribute__((aligned(16))) _Float16 sB[128 * 32];
    int tid = threadIdx.x;
    int W = tid >> 6, lane = tid & 63, quad = lane >> 4, l15 = lane & 15;
    int m0 = blockIdx.y * 128, n0 = blockIdx.x * 128;
    int wr = (W >> 1) * 64, wc = (W & 1) * 64;
    floatx4 acc[4][4] = {};

    for (int kt = 0; kt < K / 32; ++kt) {
        int k0 = kt * 32;
#pragma unroll
        for (int rho = 0; rho < 2; ++rho) {
            int lin = rho * 256 + tid;                 // 16B chunk id, tile row-major
            const _Float16* gA = A + (size_t)(m0 + (lin >> 2)) * K + k0 + (lin & 3) * 8;
            const _Float16* gB = BT + (size_t)(n0 + (lin >> 2)) * K + k0 + (lin & 3) * 8;
            int ldsoff = __builtin_amdgcn_readfirstlane((rho * 256 + W * 64) * 16);
            gl2lds16(gA, (char*)sA + ldsoff);
            gl2lds16(gB, (char*)sB + ldsoff);
        }
        __syncthreads();
        half8 a[4], b[4];
#pragma unroll
        for (int rf = 0; rf < 4; ++rf)
            a[rf] = *(const half8*)(sA + (wr + rf * 16 + l15) * 32 + quad * 8);
#pragma unroll
        for (int cf = 0; cf < 4; ++cf)
            b[cf] = *(const half8*)(sB + (wc + cf * 16 + l15) * 32 + quad * 8);
#pragma unroll
        for (int rf = 0; rf < 4; ++rf)
#pragma unroll
            for (int cf = 0; cf < 4; ++cf)
                acc[rf][cf] = __builtin_amdgcn_mfma_f32_16x16x32_f16(a[rf], b[cf], acc[rf][cf], 0, 0, 0);
        __syncthreads();
    }
#pragma unroll
    for (int cf = 0; cf < 4; ++cf) {
        int gn = n0 + wc + cf * 16 + l15;
        float bv = bias[gn];
#pragma unroll
        for (int rf = 0; rf < 4; ++rf) {
            int gmBase = m0 + wr + rf * 16 + quad * 4;
#pragma unroll
            for (int r = 0; r < 4; ++r) {
                float v = acc[rf][cf][r] + bv;
                size_t off = (size_t)(gmBase + r) * N + gn;
                if (F16OUT) ((_Float16*)Cout)[off] = (_Float16)v;
                else        ((float*)Cout)[off] = v;
            }
        }
    }
}

// ------------------------------- attention v3 -------------------------------
// grid (32 q-tiles, 128 bh), 512 threads = 8 waves.
// Phase1: wave w computes S^T for k in [w*128, w*128+128), exp -> E, rowsum -> lsum.
// Phase2: per-thread row sweep, p = relu(e*inv - t) with packed fp16.
// Phase3: wave w -> output tile (q-half w>>2, d-quarter w&3) over full k=1024.
// LDS: E = 32 q-rows x 1024 k fp16 (64KB), xor-swizzled (16B granular); lsum 8x32 f32.
__device__ __forceinline__ int esw(int row, int colByte) {
    return row * 2048 + (colByte ^ ((row & 7) << 4));
}

__global__ __launch_bounds__(512, 4) void attn(const _Float16* __restrict__ qkv,
                                               const _Float16* __restrict__ vT,
                                               _Float16* __restrict__ y) {
    __shared__ __attribute__((aligned(16))) _Float16 E[32 * 1024];
    __shared__ float lsum[8][32];
    char* Eb = (char*)E;
    int tid = threadIdx.x;
    int W = tid >> 6, lane = tid & 63, quad = lane >> 4, l15 = lane & 15;
    int qt = blockIdx.x, bh = blockIdx.y;
    int b = bh >> 4, h = bh & 15;
    int q0 = qt * 32;

    // --- Q as B-fragments (B[k=quad*8+j][n=l15]): n = q-row, k = d ---
    half8 bq[2][2];
#pragma unroll
    for (int nf = 0; nf < 2; ++nf)
#pragma unroll
        for (int ks = 0; ks < 2; ++ks)
            bq[nf][ks] = *(const half8*)(qkv + (size_t)(b * 1024 + q0 + nf * 16 + l15) * 3072 +
                                         h * 64 + ks * 32 + quad * 8);

    // --- Phase 1: S^T = K.Q^T (scaled), e = exp(s) -> E; rowsum partials in regs ---
    float lpart[2] = {0.f, 0.f};   // lane's partial rowsum for q = nf*16 + l15
#pragma unroll 4
    for (int mt = 0; mt < 8; ++mt) {
        int tk = W * 128 + mt * 16 + l15;
        const _Float16* kp = qkv + (size_t)(b * 1024 + tk) * 3072 + 1024 + h * 64 + quad * 8;
        half8 ak0 = *(const half8*)(kp);
        half8 ak1 = *(const half8*)(kp + 32);
#pragma unroll
        for (int nf = 0; nf < 2; ++nf) {
            floatx4 s = {};
            s = __builtin_amdgcn_mfma_f32_16x16x32_f16(ak0, bq[nf][0], s, 0, 0, 0);
            s = __builtin_amdgcn_mfma_f32_16x16x32_f16(ak1, bq[nf][1], s, 0, 0, 0);
            half4_t h4;
#pragma unroll
            for (int r = 0; r < 4; ++r) {
                float e = __expf(fminf(s[r] * 0.125f, 10.0f));  // exp(10)=22026 < fp16 max
                lpart[nf] += e;
                h4[r] = (_Float16)e;
            }
            int q = nf * 16 + l15;
            int kbyte = (W * 128 + mt * 16 + quad * 4) * 2;
            *(half4_t*)(Eb + q * 2048 + (kbyte ^ ((q & 7) << 4))) = h4;
        }
    }
    // reduce partials over the 4 quads (lanes sharing l15)
#pragma unroll
    for (int nf = 0; nf < 2; ++nf) {
        lpart[nf] += __shfl_xor(lpart[nf], 16);
        lpart[nf] += __shfl_xor(lpart[nf], 32);
    }
    if (lane < 16) {
        lsum[W][l15] = lpart[0];
        lsum[W][16 + l15] = lpart[1];
    }
    __syncthreads();

    // --- Phase 2: p = relu(e*inv - t), packed fp16, one row-segment per thread ---
    {
        int row = tid >> 4, seg = tid & 15;
        float l = 0.f;
#pragma unroll
        for (int w = 0; w < 8; ++w) l += lsum[w][row];
        _Float16 invh = (_Float16)(1.0f / l);
        half8 inv8, t8;
#pragma unroll
        for (int j = 0; j < 8; ++j) { inv8[j] = invh; t8[j] = (_Float16)(-0.001f); }
#pragma unroll
        for (int c = 0; c < 8; ++c) {
            half8* p = (half8*)(Eb + esw(row, c * 256 + seg * 16));
            half8 hv = *p;
            hv = hv * inv8 + t8;                       // v_pk_fma_f16
            hv = __builtin_elementwise_max(hv, (half8)(_Float16)0.f);  // v_pk_max_f16
            *p = hv;
        }
    }
    __syncthreads();

    // --- Phase 3: wave tile (q-half rf, d-quarter cf) over full k = 1024 ---
    {
        int rf = W >> 2, cf = W & 3;
        const _Float16* vbase = vT + (size_t)(bh * 64 + cf * 16 + l15) * 1024 + quad * 8;
        floatx4 acc0 = {}, acc1 = {};
#pragma unroll 8
        for (int kt = 0; kt < 32; kt += 2) {
            half8 ap0 = *(const half8*)(Eb + esw(rf * 16 + l15, (kt * 32 + quad * 8) * 2));
            half8 bv0 = *(const half8*)(vbase + kt * 32);
            half8 ap1 = *(const half8*)(Eb + esw(rf * 16 + l15, ((kt + 1) * 32 + quad * 8) * 2));
            half8 bv1 = *(const half8*)(vbase + (kt + 1) * 32);
            acc0 = __builtin_amdgcn_mfma_f32_16x16x32_f16(ap0, bv0, acc0, 0, 0, 0);
            acc1 = __builtin_amdgcn_mfma_f32_16x16x32_f16(ap1, bv1, acc1, 0, 0, 0);
        }
        acc0 += acc1;
        // C-layout: col(l15) = d within quarter, row(quad*4+r) = q within half
#pragma unroll
        for (int r = 0; r < 4; ++r) {
            int q = q0 + rf * 16 + quad * 4 + r;
            int d = h * 64 + cf * 16 + l15;
            y[(size_t)(b * 1024 + q) * 1024 + d] = (_Float16)acc0[r];
        }
    }
}

// ------------------------------- launcher -------------------------------
extern "C" void kernel_launch(void* const* d_in, const int* in_sizes, int n_in,
                              void* d_out, int out_size, void* d_ws, size_t ws_size,
                              hipStream_t stream) {
    const float* x  = (const float*)d_in[0];
    const float* wa = (const float*)d_in[1];
    const float* ba = (const float*)d_in[2];
    const float* wp = (const float*)d_in[3];
    const float* bp = (const float*)d_in[4];
    float* out = (float*)d_out;

    char* ws = (char*)d_ws;
    _Float16* qkv = (_Float16*)(ws);                    // 48 MiB
    _Float16* vT  = (_Float16*)(ws + 50331648);         // 16 MiB
    _Float16* xh  = (_Float16*)(ws + 67108864);         // 16 MiB (reused as y)
    _Float16* waT = (_Float16*)(ws + 83886080);         // 6 MiB
    _Float16* wpT = (_Float16*)(ws + 90177536);         // 2 MiB

    conv_x<<<4096, 256, 0, stream>>>((const float4*)x, xh, 8388608 / 4);
    tconv<<<dim3(48, 16), 256, 0, stream>>>(wa, waT, 1024, 3072);
    tconv<<<dim3(16, 16), 256, 0, stream>>>(wp, wpT, 1024, 1024);
    gemm_tn<true><<<dim3(24, 64), 256, 0, stream>>>(xh, waT, ba, (void*)qkv, 3072);
    vtrans<<<dim3(16, 128), 256, 0, stream>>>(qkv, vT);
    attn<<<dim3(32, 128), 512, 0, stream>>>(qkv, vT, xh);
    gemm_tn<false><<<dim3(8, 64), 256, 0, stream>>>(xh, wpT, bp, (void*)out, 1024);
}